// Round 4
// baseline (698.995 us; speedup 1.0000x reference)
//
#include <hip/hip_runtime.h>
#include <stdint.h>

// ---------------- common types / helpers ----------------

typedef short bf16x8 __attribute__((ext_vector_type(8)));
typedef float f32x4 __attribute__((ext_vector_type(4)));

struct alignas(8) us4 { unsigned short x, y, z, w; };

__device__ __forceinline__ unsigned short f32_to_bf16(float f) {
  union { float f; uint32_t u; } v; v.f = f;
  uint32_t u = v.u;
  uint32_t r = (u + 0x7fffu + ((u >> 16) & 1u)) >> 16;  // RNE
  return (unsigned short)r;
}

__device__ __forceinline__ float bf16_to_f32(unsigned short h) {
  union { uint32_t u; float f; } v; v.u = ((uint32_t)h) << 16;
  return v.f;
}

// pack two f32 into bf16x2 by truncation: one v_perm_b32
__device__ __forceinline__ uint32_t pack_bf16_trunc(float lo, float hi) {
  union { float f; uint32_t u; } a, b; a.f = lo; b.f = hi;
  return __builtin_amdgcn_perm(b.u, a.u, 0x07060302u);  // [lo.hi16, hi.hi16]
}

// async global->LDS, 16B per lane; LDS dest is wave-uniform base + lane*16
__device__ __forceinline__ void g2l16(const unsigned short* g, unsigned short* l) {
  __builtin_amdgcn_global_load_lds((__attribute__((address_space(1))) void*)g,
                                   (__attribute__((address_space(3))) void*)l,
                                   16, 0, 0);
}

// ---------------- problem constants ----------------
// B=128, S=512, D=768, NH=8, HD=96, HID=384

#define N_X   50331648   // 128*512*768
#define N_P   589824     // 8*96*768
#define N_W1  294912     // 8*384*96
#define N_W2  294912     // 8*96*384
#define N_HI  50331648   // 8*128*512*96

// ---------------- kernel 0: fp32 -> bf16 cast ----------------

__global__ __launch_bounds__(256) void cast_f32_bf16(
    const float* __restrict__ src, unsigned short* __restrict__ dst, int n4) {
  int idx = blockIdx.x * 256 + threadIdx.x;
  if (idx >= n4) return;
  float4 v = ((const float4*)src)[idx];
  us4 o;
  o.x = f32_to_bf16(v.x);
  o.y = f32_to_bf16(v.y);
  o.z = f32_to_bf16(v.z);
  o.w = f32_to_bf16(v.w);
  ((us4*)dst)[idx] = o;
}

// ---------------- kernel 1: Hi = X @ P^T + bP ----------------
// (unchanged — isolating the mlp_logits rewrite)

__global__ __launch_bounds__(256) void gemm_hi(
    const unsigned short* __restrict__ Xbf,
    const unsigned short* __restrict__ Pbf,
    const float* __restrict__ bP,
    unsigned short* __restrict__ Hi) {
  __shared__ __align__(16) unsigned short As[128 * 32];
  __shared__ __align__(16) unsigned short Bs[128 * 32];

  const int tid = threadIdx.x;
  const int w = tid >> 6;
  const int lane = tid & 63;
  const int r = lane & 15;
  const int q = lane >> 4;
  const int bn = blockIdx.x;  // 0..5
  const int bm = blockIdx.y;  // 0..511
  const int wr = w >> 1, wc = w & 1;

  f32x4 acc[4][4];
#pragma unroll
  for (int a = 0; a < 4; ++a)
#pragma unroll
    for (int c = 0; c < 4; ++c) acc[a][c] = (f32x4){0.f, 0.f, 0.f, 0.f};

  const int ldr = lane >> 2;
  const int ldc = (lane & 3) * 8;
  const unsigned short* Abase = Xbf + (size_t)(bm * 128) * 768 + ldc;
  const unsigned short* Bbase = Pbf + (size_t)(bn * 128) * 768 + ldc;

  for (int k0 = 0; k0 < 768; k0 += 32) {
    __syncthreads();
    g2l16(Abase + (size_t)(w * 16 + ldr) * 768 + k0, &As[w * 512]);
    g2l16(Abase + (size_t)(64 + w * 16 + ldr) * 768 + k0, &As[(4 + w) * 512]);
    g2l16(Bbase + (size_t)(w * 16 + ldr) * 768 + k0, &Bs[w * 512]);
    g2l16(Bbase + (size_t)(64 + w * 16 + ldr) * 768 + k0, &Bs[(4 + w) * 512]);
    __syncthreads();

    bf16x8 af[4], bfr[4];
#pragma unroll
    for (int t = 0; t < 4; ++t)
      af[t] = *(const bf16x8*)&As[(wr * 64 + t * 16 + r) * 32 + q * 8];
#pragma unroll
    for (int t = 0; t < 4; ++t)
      bfr[t] = *(const bf16x8*)&Bs[(wc * 64 + t * 16 + r) * 32 + q * 8];
#pragma unroll
    for (int mt = 0; mt < 4; ++mt)
#pragma unroll
      for (int nt = 0; nt < 4; ++nt)
        acc[mt][nt] = __builtin_amdgcn_mfma_f32_16x16x32_bf16(
            af[mt], bfr[nt], acc[mt][nt], 0, 0, 0);
  }

  const int bb = bm >> 2;
  const int sb = (bm & 3) * 128 + wr * 64;
#pragma unroll
  for (int nt = 0; nt < 4; ++nt) {
    const int n0 = bn * 128 + wc * 64 + nt * 16;
    const int hd = n0 / 96;
    const int h = n0 - hd * 96 + r;
    const float bias = bP[n0 + r];
    unsigned short* obase = Hi + (size_t)(hd * 128 + bb) * 512 * 96 + h;
#pragma unroll
    for (int mt = 0; mt < 4; ++mt) {
#pragma unroll
      for (int rg = 0; rg < 4; ++rg) {
        const int s = sb + mt * 16 + q * 4 + rg;
        obase[(size_t)s * 96] = f32_to_bf16(acc[mt][nt][rg] + bias);
      }
    }
  }
}

// ---------------- kernel 2: fused per-head MLP -> logits (v3, barrier-free) ----------------
// Block = (head, batch, 128-token chunk); 4096 blocks x 256 thr. NO LDS, NO barriers.
//  - Y b-frags live in registers (loaded once per wave, 2 s-tiles x 3 k-chunks).
//  - W1 a-frags / W2 a-frags loaded per-lane straight from global (L2-resident:
//    144KB/head shared by 512 consecutive blocks).
//  - GEMM2 (F^T tile pair) -> relu+bias -> bf16 pack -> in-wave quad permutation
//    (ds_bpermute) converts C-layout directly to GEMM3 B-operand layout:
//    b-frag dword d of lane (r,q) = dword (d&1) of f-tile 2kb+(q>>1) from lane
//    32(q&1)+16(d>>1)+r. F never touches memory.
//  - acc3 accumulates K=384 across 4 phases; epilogue +b2, b64 stores.

__global__ __launch_bounds__(256, 3) void mlp_logits(
    const unsigned short* __restrict__ Hi,
    const unsigned short* __restrict__ W1bf,  // (8*384) x 96
    const unsigned short* __restrict__ W2bf,  // (8*96) x 384
    const float* __restrict__ b1,             // 8*384
    const float* __restrict__ b2,             // 8*96
    unsigned short* __restrict__ Alog) {
  const int x = blockIdx.x;
  const int c = x & 3;
  const int b = (x >> 2) & 127;
  const int hd = x >> 9;  // head slowest -> weight L2 sharing

  const int tid = threadIdx.x;
  const int w = tid >> 6;
  const int lane = tid & 63;
  const int r = lane & 15;
  const int q = lane >> 4;

  const unsigned short* ybase = Hi + ((size_t)(hd * 128 + b) * 512 + c * 128) * 96;
  const unsigned short* w1h = W1bf + (size_t)hd * 384 * 96;
  const unsigned short* w2h = W2bf + (size_t)hd * 96 * 384;
  const float* b1h = b1 + hd * 384;
  const float* b2h = b2 + hd * 96;

  // Y fragments (B-operand): stiles 2w, 2w+1; [sp][kb]; kept in regs all kernel
  bf16x8 yf[2][3];
#pragma unroll
  for (int sp = 0; sp < 2; ++sp)
#pragma unroll
    for (int kb = 0; kb < 3; ++kb)
      yf[sp][kb] =
          *(const bf16x8*)&ybase[((w * 2 + sp) * 16 + r) * 96 + kb * 32 + q * 8];

  // bpermute source-lane byte addresses: q_s = 2*(q&1) (+1 for _b)
  const int vaddr_a = (((lane >> 4) & 1) * 32 + r) * 4;
  const int vaddr_b = vaddr_a + 64;
  const bool hiq = lane >= 32;  // q>=2 -> take f-tile 2kb+1

  f32x4 acc3[2][6];
#pragma unroll
  for (int sp = 0; sp < 2; ++sp)
#pragma unroll
    for (int nt = 0; nt < 6; ++nt) acc3[sp][nt] = (f32x4){0.f, 0.f, 0.f, 0.f};

  for (int ph = 0; ph < 4; ++ph) {
#pragma unroll
    for (int kb2 = 0; kb2 < 3; ++kb2) {
      // ---- GEMM2 for f-tiles 2*kb2, 2*kb2+1 (M=32 f, N=32 s, K=96) ----
      uint32_t PX[2][2], PY[2][2];  // [f-half][sp]
#pragma unroll
      for (int fh = 0; fh < 2; ++fh) {
        const int ft = kb2 * 2 + fh;
        const int frow = ph * 96 + ft * 16 + r;
        f32x4 a2[2];
        a2[0] = (f32x4){0.f, 0.f, 0.f, 0.f};
        a2[1] = (f32x4){0.f, 0.f, 0.f, 0.f};
#pragma unroll
        for (int kb = 0; kb < 3; ++kb) {
          bf16x8 w1f = *(const bf16x8*)&w1h[(size_t)frow * 96 + kb * 32 + q * 8];
#pragma unroll
          for (int sp = 0; sp < 2; ++sp)
            a2[sp] = __builtin_amdgcn_mfma_f32_16x16x32_bf16(w1f, yf[sp][kb],
                                                             a2[sp], 0, 0, 0);
        }
        const float4 bv = *(const float4*)&b1h[ph * 96 + ft * 16 + q * 4];
#pragma unroll
        for (int sp = 0; sp < 2; ++sp) {
          float v0 = fmaxf(a2[sp][0] + bv.x, 0.f);
          float v1 = fmaxf(a2[sp][1] + bv.y, 0.f);
          float v2 = fmaxf(a2[sp][2] + bv.z, 0.f);
          float v3 = fmaxf(a2[sp][3] + bv.w, 0.f);
          PX[fh][sp] = pack_bf16_trunc(v0, v1);  // f = ft*16+4q+{0,1}
          PY[fh][sp] = pack_bf16_trunc(v2, v3);  // f = ft*16+4q+{2,3}
        }
      }
      // ---- W2 a-frags for this 32-wide k-chunk (shared across sp) ----
      bf16x8 w2f[6];
#pragma unroll
      for (int nt = 0; nt < 6; ++nt)
        w2f[nt] = *(const bf16x8*)&w2h[(size_t)(nt * 16 + r) * 384 + ph * 96 +
                                       kb2 * 32 + q * 8];
      // ---- shuffle F^T C-layout -> B-operand layout, then GEMM3 ----
#pragma unroll
      for (int sp = 0; sp < 2; ++sp) {
        union { bf16x8 v; uint32_t d[4]; } bb;
        uint32_t t0, t1;
        t0 = (uint32_t)__builtin_amdgcn_ds_bpermute(vaddr_a, (int)PX[0][sp]);
        t1 = (uint32_t)__builtin_amdgcn_ds_bpermute(vaddr_a, (int)PX[1][sp]);
        bb.d[0] = hiq ? t1 : t0;
        t0 = (uint32_t)__builtin_amdgcn_ds_bpermute(vaddr_a, (int)PY[0][sp]);
        t1 = (uint32_t)__builtin_amdgcn_ds_bpermute(vaddr_a, (int)PY[1][sp]);
        bb.d[1] = hiq ? t1 : t0;
        t0 = (uint32_t)__builtin_amdgcn_ds_bpermute(vaddr_b, (int)PX[0][sp]);
        t1 = (uint32_t)__builtin_amdgcn_ds_bpermute(vaddr_b, (int)PX[1][sp]);
        bb.d[2] = hiq ? t1 : t0;
        t0 = (uint32_t)__builtin_amdgcn_ds_bpermute(vaddr_b, (int)PY[0][sp]);
        t1 = (uint32_t)__builtin_amdgcn_ds_bpermute(vaddr_b, (int)PY[1][sp]);
        bb.d[3] = hiq ? t1 : t0;
#pragma unroll
        for (int nt = 0; nt < 6; ++nt)
          acc3[sp][nt] = __builtin_amdgcn_mfma_f32_16x16x32_bf16(
              w2f[nt], bb.v, acc3[sp][nt], 0, 0, 0);
      }
    }
  }

  // epilogue: +b2, pack 4 h-consecutive bf16, 8B stores
  unsigned short* aout = Alog + ((size_t)(hd * 128 + b) * 512 + c * 128) * 96;
#pragma unroll
  for (int nt = 0; nt < 6; ++nt) {
    const float4 bv = *(const float4*)&b2h[nt * 16 + q * 4];
#pragma unroll
    for (int sp = 0; sp < 2; ++sp) {
      const int s = (w * 2 + sp) * 16 + r;
      uint2 pk;
      pk.x = (uint32_t)f32_to_bf16(acc3[sp][nt][0] + bv.x) |
             ((uint32_t)f32_to_bf16(acc3[sp][nt][1] + bv.y) << 16);
      pk.y = (uint32_t)f32_to_bf16(acc3[sp][nt][2] + bv.z) |
             ((uint32_t)f32_to_bf16(acc3[sp][nt][3] + bv.w) << 16);
      *(uint2*)&aout[(size_t)s * 96 + nt * 16 + q * 4] = pk;
    }
  }
}

// ---------------- kernel 3: masked softmax over S + weighted pool ----------------
// (unchanged from R1)

__global__ __launch_bounds__(384) void softpool(
    const unsigned short* __restrict__ Hi,
    const unsigned short* __restrict__ Alog,
    const float* __restrict__ mask,  // B x S
    float* __restrict__ out) {       // B x 768
  __shared__ float bias[512];
  __shared__ float redl[32][96];
  __shared__ float redv[32][96];
  __shared__ float mfin[96];

  const int x = blockIdx.x;  // i*128 + b
  const int hd = x >> 7;
  const int b = x & 127;
  const int tid = threadIdx.x;
  const int g = tid / 12;
  const int t12 = tid - g * 12;
  const int h8 = t12 * 8;

  for (int s = tid; s < 512; s += 384)
    bias[s] = mask[b * 512 + s] > 0.5f ? 0.f : -1e30f;
  __syncthreads();

  const unsigned short* abase = Alog + (size_t)x * 512 * 96;
  const unsigned short* hbase = Hi + (size_t)x * 512 * 96;

  float m[8];
#pragma unroll
  for (int j = 0; j < 8; ++j) m[j] = -3e30f;
#pragma unroll
  for (int it = 0; it < 16; ++it) {
    const int s = g * 16 + it;
    bf16x8 a = *(const bf16x8*)&abase[(size_t)s * 96 + h8];
    const float bs = bias[s];
#pragma unroll
    for (int j = 0; j < 8; ++j)
      m[j] = fmaxf(m[j], bf16_to_f32((unsigned short)a[j]) + bs);
  }
#pragma unroll
  for (int j = 0; j < 8; ++j) redl[g][h8 + j] = m[j];
  __syncthreads();
  if (tid < 96) {
    float mm = -3e30f;
#pragma unroll
    for (int gg = 0; gg < 32; ++gg) mm = fmaxf(mm, redl[gg][tid]);
    mfin[tid] = mm;
  }
  __syncthreads();
  float mf[8];
#pragma unroll
  for (int j = 0; j < 8; ++j) mf[j] = mfin[h8 + j];
  __syncthreads();

  float l[8], v[8];
#pragma unroll
  for (int j = 0; j < 8; ++j) { l[j] = 0.f; v[j] = 0.f; }
#pragma unroll
  for (int it = 0; it < 16; ++it) {
    const int s = g * 16 + it;
    bf16x8 a = *(const bf16x8*)&abase[(size_t)s * 96 + h8];
    bf16x8 hv = *(const bf16x8*)&hbase[(size_t)s * 96 + h8];
    const float bs = bias[s];
#pragma unroll
    for (int j = 0; j < 8; ++j) {
      float e = __expf(bf16_to_f32((unsigned short)a[j]) + bs - mf[j]);
      l[j] += e;
      v[j] += e * bf16_to_f32((unsigned short)hv[j]);
    }
  }
#pragma unroll
  for (int j = 0; j < 8; ++j) {
    redl[g][h8 + j] = l[j];
    redv[g][h8 + j] = v[j];
  }
  __syncthreads();
  if (tid < 96) {
    float ls = 0.f, vs = 0.f;
#pragma unroll
    for (int gg = 0; gg < 32; ++gg) { ls += redl[gg][tid]; vs += redv[gg][tid]; }
    out[b * 768 + hd * 96 + tid] = vs / ls;
  }
}

// ---------------- launcher ----------------

extern "C" void kernel_launch(void* const* d_in, const int* in_sizes, int n_in,
                              void* d_out, int out_size, void* d_ws, size_t ws_size,
                              hipStream_t stream) {
  const float* X    = (const float*)d_in[0];
  const float* mask = (const float*)d_in[1];
  const float* P    = (const float*)d_in[2];
  const float* bP   = (const float*)d_in[3];
  const float* W1   = (const float*)d_in[4];
  const float* b1   = (const float*)d_in[5];
  const float* W2   = (const float*)d_in[6];
  const float* b2   = (const float*)d_in[7];
  float* out = (float*)d_out;
  (void)in_sizes; (void)n_in; (void)out_size; (void)ws_size;

  unsigned short* Xbf  = (unsigned short*)d_ws;
  unsigned short* Pbf  = Xbf + N_X;
  unsigned short* W1bf = Pbf + N_P;
  unsigned short* W2bf = W1bf + N_W1;
  unsigned short* Hi   = W2bf + N_W2;
  unsigned short* Alog = Hi + N_HI;

  cast_f32_bf16<<<N_X / 4 / 256, 256, 0, stream>>>(X, Xbf, N_X / 4);
  cast_f32_bf16<<<N_P / 4 / 256, 256, 0, stream>>>(P, Pbf, N_P / 4);
  cast_f32_bf16<<<N_W1 / 4 / 256, 256, 0, stream>>>(W1, W1bf, N_W1 / 4);
  cast_f32_bf16<<<N_W2 / 4 / 256, 256, 0, stream>>>(W2, W2bf, N_W2 / 4);

  gemm_hi<<<dim3(6, 512), 256, 0, stream>>>(Xbf, Pbf, bP, Hi);
  mlp_logits<<<8 * 128 * 4, 256, 0, stream>>>(Hi, W1bf, W2bf, b1, b2, Alog);
  softpool<<<8 * 128, 384, 0, stream>>>(Hi, Alog, mask, out);
}

// Round 5
// 629.125 us; speedup vs baseline: 1.1111x; 1.1111x over previous
//
#include <hip/hip_runtime.h>
#include <stdint.h>

// ---------------- common types / helpers ----------------

typedef short bf16x8 __attribute__((ext_vector_type(8)));
typedef float f32x4 __attribute__((ext_vector_type(4)));

struct alignas(8) us4 { unsigned short x, y, z, w; };

__device__ __forceinline__ unsigned short f32_to_bf16(float f) {
  union { float f; uint32_t u; } v; v.f = f;
  uint32_t u = v.u;
  uint32_t r = (u + 0x7fffu + ((u >> 16) & 1u)) >> 16;  // RNE
  return (unsigned short)r;
}

__device__ __forceinline__ float bf16_to_f32(unsigned short h) {
  union { uint32_t u; float f; } v; v.u = ((uint32_t)h) << 16;
  return v.f;
}

// pack two f32 into bf16x2 by truncation: one v_perm_b32
__device__ __forceinline__ uint32_t pack_bf16_trunc(float lo, float hi) {
  union { float f; uint32_t u; } a, b; a.f = lo; b.f = hi;
  return __builtin_amdgcn_perm(b.u, a.u, 0x07060302u);  // [lo.hi16, hi.hi16]
}

// async global->LDS, 16B per lane; LDS dest is wave-uniform base + lane*16
__device__ __forceinline__ void g2l16(const unsigned short* g, unsigned short* l) {
  __builtin_amdgcn_global_load_lds((__attribute__((address_space(1))) void*)g,
                                   (__attribute__((address_space(3))) void*)l,
                                   16, 0, 0);
}

// ---------------- problem constants ----------------
// B=128, S=512, D=768, NH=8, HD=96, HID=384

#define N_X   50331648   // 128*512*768
#define N_P   589824     // 8*96*768
#define N_W1  294912     // 8*384*96
#define N_W2  294912     // 8*96*384
#define N_HI  50331648   // 8*128*512*96

// ---------------- kernel 0: fp32 -> bf16 cast ----------------

__global__ __launch_bounds__(256) void cast_f32_bf16(
    const float* __restrict__ src, unsigned short* __restrict__ dst, int n4) {
  int idx = blockIdx.x * 256 + threadIdx.x;
  if (idx >= n4) return;
  float4 v = ((const float4*)src)[idx];
  us4 o;
  o.x = f32_to_bf16(v.x);
  o.y = f32_to_bf16(v.y);
  o.z = f32_to_bf16(v.z);
  o.w = f32_to_bf16(v.w);
  ((us4*)dst)[idx] = o;
}

// ---------------- kernel 1: Hi = X @ P^T + bP ----------------
// (unchanged — isolating the mlp_logits rewrite)

__global__ __launch_bounds__(256) void gemm_hi(
    const unsigned short* __restrict__ Xbf,
    const unsigned short* __restrict__ Pbf,
    const float* __restrict__ bP,
    unsigned short* __restrict__ Hi) {
  __shared__ __align__(16) unsigned short As[128 * 32];
  __shared__ __align__(16) unsigned short Bs[128 * 32];

  const int tid = threadIdx.x;
  const int w = tid >> 6;
  const int lane = tid & 63;
  const int r = lane & 15;
  const int q = lane >> 4;
  const int bn = blockIdx.x;  // 0..5
  const int bm = blockIdx.y;  // 0..511
  const int wr = w >> 1, wc = w & 1;

  f32x4 acc[4][4];
#pragma unroll
  for (int a = 0; a < 4; ++a)
#pragma unroll
    for (int c = 0; c < 4; ++c) acc[a][c] = (f32x4){0.f, 0.f, 0.f, 0.f};

  const int ldr = lane >> 2;
  const int ldc = (lane & 3) * 8;
  const unsigned short* Abase = Xbf + (size_t)(bm * 128) * 768 + ldc;
  const unsigned short* Bbase = Pbf + (size_t)(bn * 128) * 768 + ldc;

  for (int k0 = 0; k0 < 768; k0 += 32) {
    __syncthreads();
    g2l16(Abase + (size_t)(w * 16 + ldr) * 768 + k0, &As[w * 512]);
    g2l16(Abase + (size_t)(64 + w * 16 + ldr) * 768 + k0, &As[(4 + w) * 512]);
    g2l16(Bbase + (size_t)(w * 16 + ldr) * 768 + k0, &Bs[w * 512]);
    g2l16(Bbase + (size_t)(64 + w * 16 + ldr) * 768 + k0, &Bs[(4 + w) * 512]);
    __syncthreads();

    bf16x8 af[4], bfr[4];
#pragma unroll
    for (int t = 0; t < 4; ++t)
      af[t] = *(const bf16x8*)&As[(wr * 64 + t * 16 + r) * 32 + q * 8];
#pragma unroll
    for (int t = 0; t < 4; ++t)
      bfr[t] = *(const bf16x8*)&Bs[(wc * 64 + t * 16 + r) * 32 + q * 8];
#pragma unroll
    for (int mt = 0; mt < 4; ++mt)
#pragma unroll
      for (int nt = 0; nt < 4; ++nt)
        acc[mt][nt] = __builtin_amdgcn_mfma_f32_16x16x32_bf16(
            af[mt], bfr[nt], acc[mt][nt], 0, 0, 0);
  }

  const int bb = bm >> 2;
  const int sb = (bm & 3) * 128 + wr * 64;
#pragma unroll
  for (int nt = 0; nt < 4; ++nt) {
    const int n0 = bn * 128 + wc * 64 + nt * 16;
    const int hd = n0 / 96;
    const int h = n0 - hd * 96 + r;
    const float bias = bP[n0 + r];
    unsigned short* obase = Hi + (size_t)(hd * 128 + bb) * 512 * 96 + h;
#pragma unroll
    for (int mt = 0; mt < 4; ++mt) {
#pragma unroll
      for (int rg = 0; rg < 4; ++rg) {
        const int s = sb + mt * 16 + q * 4 + rg;
        obase[(size_t)s * 96] = f32_to_bf16(acc[mt][nt][rg] + bias);
      }
    }
  }
}

// ---------------- kernel 2: fused per-head MLP -> logits (v4) ----------------
// Hybrid of R2 (block-level LDS weight staging via g2l16) and R3 (Y in regs,
// F^T -> B-operand via in-wave ds_bpermute; F never touches memory).
// Per phase (96-wide quarter of HID):
//   GEMM2 (all 6 f-tiles, packs in regs) -> B1 -> stage W1(p+1) (overlaps) ->
//   GEMM3 (from Ws2) -> B2 -> stage W2(p+1) (overlaps next GEMM2).
// 9 barriers total; each drains loads issued a full GEMM-stage earlier.
// LDS 36 KB; weights staged once per BLOCK (L2 -> LDS 590 MB aggregate, not
// 2.4 GB per-wave as in v3 — that was the R3 regression).

__global__ __launch_bounds__(256, 3) void mlp_logits(
    const unsigned short* __restrict__ Hi,
    const unsigned short* __restrict__ W1bf,  // (8*384) x 96
    const unsigned short* __restrict__ W2bf,  // (8*96) x 384
    const float* __restrict__ b1,             // 8*384
    const float* __restrict__ b2,             // 8*96
    unsigned short* __restrict__ Alog) {
  __shared__ __align__(16) unsigned short Ws1[9216];  // [kb][f][32], kb over HD=96
  __shared__ __align__(16) unsigned short Ws2[9216];  // [kb][h][32], kb over phase f-chunk

  const int x = blockIdx.x;
  const int c = x & 3;
  const int b = (x >> 2) & 127;
  const int hd = x >> 9;  // head slowest -> weight L2 sharing

  const int tid = threadIdx.x;
  const int w = tid >> 6;
  const int lane = tid & 63;
  const int r = lane & 15;
  const int q = lane >> 4;

  const unsigned short* ybase = Hi + ((size_t)(hd * 128 + b) * 512 + c * 128) * 96;
  const unsigned short* w1h = W1bf + (size_t)hd * 384 * 96;
  const unsigned short* w2h = W2bf + (size_t)hd * 96 * 384;
  const float* b1h = b1 + hd * 384;
  const float* b2h = b2 + hd * 96;

  // Y fragments (B-operand): s-tiles 2w, 2w+1; kept in regs all kernel
  bf16x8 yf[2][3];
#pragma unroll
  for (int sp = 0; sp < 2; ++sp)
#pragma unroll
    for (int kb = 0; kb < 3; ++kb)
      yf[sp][kb] =
          *(const bf16x8*)&ybase[((w * 2 + sp) * 16 + r) * 96 + kb * 32 + q * 8];

  // ---- weight staging helpers (per-lane gather -> wave-uniform LDS dest) ----
  // W1 quarter phN: 96 rows f x 96 k, K-chunked [kb][f][32]; 1152 16B chunks
  auto stage_w1 = [&](int phN) {
    const unsigned short* src = w1h + (size_t)phN * 96 * 96;
#pragma unroll
    for (int cb = 0; cb < 5; ++cb) {
      const int cblk = cb * 4 + w;
      if (cblk >= 18) break;
      const int ch = cblk * 64 + lane;  // 0..1151
      const int kbf = ch >> 2, j = ch & 3;
      const int kb = kbf / 96, f = kbf - kb * 96;
      g2l16(src + (size_t)f * 96 + kb * 32 + j * 8, &Ws1[cblk * 512]);
    }
  };
  // W2 quarter phN: 96 rows h x 96 f-cols (of stride-384 rows), [kb][h][32]
  auto stage_w2 = [&](int phN) {
    const unsigned short* src = w2h + phN * 96;
#pragma unroll
    for (int cb = 0; cb < 5; ++cb) {
      const int cblk = cb * 4 + w;
      if (cblk >= 18) break;
      const int ch = cblk * 64 + lane;  // 0..1151
      const int kbf = ch >> 2, j = ch & 3;
      const int kb = kbf / 96, h = kbf - kb * 96;
      g2l16(src + (size_t)h * 384 + kb * 32 + j * 8, &Ws2[cblk * 512]);
    }
  };

  // bpermute source-lane byte addresses (verified in R3)
  const int vaddr_a = (((lane >> 4) & 1) * 32 + r) * 4;
  const int vaddr_b = vaddr_a + 64;
  const bool hiq = lane >= 32;

  f32x4 acc3[2][6];
#pragma unroll
  for (int sp = 0; sp < 2; ++sp)
#pragma unroll
    for (int nt = 0; nt < 6; ++nt) acc3[sp][nt] = (f32x4){0.f, 0.f, 0.f, 0.f};

  stage_w1(0);
  stage_w2(0);
  __syncthreads();  // W1(0)+W2(0) ready

  for (int ph = 0; ph < 4; ++ph) {
    // ---- GEMM2: F^T quarter, all 6 f-tiles x 2 s-tiles, packs -> regs ----
    uint32_t PX[6][2], PY[6][2];
#pragma unroll
    for (int ft = 0; ft < 6; ++ft) {
      f32x4 a2[2];
      a2[0] = (f32x4){0.f, 0.f, 0.f, 0.f};
      a2[1] = (f32x4){0.f, 0.f, 0.f, 0.f};
#pragma unroll
      for (int kb = 0; kb < 3; ++kb) {
        bf16x8 w1f = *(const bf16x8*)&Ws1[(kb * 96 + ft * 16 + r) * 32 + q * 8];
#pragma unroll
        for (int sp = 0; sp < 2; ++sp)
          a2[sp] = __builtin_amdgcn_mfma_f32_16x16x32_bf16(w1f, yf[sp][kb],
                                                           a2[sp], 0, 0, 0);
      }
      const float4 bv = *(const float4*)&b1h[ph * 96 + ft * 16 + q * 4];
#pragma unroll
      for (int sp = 0; sp < 2; ++sp) {
        float v0 = fmaxf(a2[sp][0] + bv.x, 0.f);
        float v1 = fmaxf(a2[sp][1] + bv.y, 0.f);
        float v2 = fmaxf(a2[sp][2] + bv.z, 0.f);
        float v3 = fmaxf(a2[sp][3] + bv.w, 0.f);
        PX[ft][sp] = pack_bf16_trunc(v0, v1);
        PY[ft][sp] = pack_bf16_trunc(v2, v3);
      }
    }
    __syncthreads();            // B1: all waves done reading Ws1
    if (ph < 3) stage_w1(ph + 1);  // overlaps GEMM3

    // ---- GEMM3: permute F^T -> B-operand, K=96 this phase ----
#pragma unroll
    for (int kb2 = 0; kb2 < 3; ++kb2) {
      bf16x8 w2f[6];
#pragma unroll
      for (int nt = 0; nt < 6; ++nt)
        w2f[nt] = *(const bf16x8*)&Ws2[(kb2 * 96 + nt * 16 + r) * 32 + q * 8];
#pragma unroll
      for (int sp = 0; sp < 2; ++sp) {
        union { bf16x8 v; uint32_t d[4]; } bb;
        uint32_t t0, t1;
        t0 = (uint32_t)__builtin_amdgcn_ds_bpermute(vaddr_a, (int)PX[kb2 * 2][sp]);
        t1 = (uint32_t)__builtin_amdgcn_ds_bpermute(vaddr_a, (int)PX[kb2 * 2 + 1][sp]);
        bb.d[0] = hiq ? t1 : t0;
        t0 = (uint32_t)__builtin_amdgcn_ds_bpermute(vaddr_a, (int)PY[kb2 * 2][sp]);
        t1 = (uint32_t)__builtin_amdgcn_ds_bpermute(vaddr_a, (int)PY[kb2 * 2 + 1][sp]);
        bb.d[1] = hiq ? t1 : t0;
        t0 = (uint32_t)__builtin_amdgcn_ds_bpermute(vaddr_b, (int)PX[kb2 * 2][sp]);
        t1 = (uint32_t)__builtin_amdgcn_ds_bpermute(vaddr_b, (int)PX[kb2 * 2 + 1][sp]);
        bb.d[2] = hiq ? t1 : t0;
        t0 = (uint32_t)__builtin_amdgcn_ds_bpermute(vaddr_b, (int)PY[kb2 * 2][sp]);
        t1 = (uint32_t)__builtin_amdgcn_ds_bpermute(vaddr_b, (int)PY[kb2 * 2 + 1][sp]);
        bb.d[3] = hiq ? t1 : t0;
#pragma unroll
        for (int nt = 0; nt < 6; ++nt)
          acc3[sp][nt] = __builtin_amdgcn_mfma_f32_16x16x32_bf16(
              w2f[nt], bb.v, acc3[sp][nt], 0, 0, 0);
      }
    }
    __syncthreads();            // B2: all waves done reading Ws2
    if (ph < 3) stage_w2(ph + 1);  // overlaps next GEMM2
  }

  // epilogue: +b2, pack 4 h-consecutive bf16, 8B stores
  unsigned short* aout = Alog + ((size_t)(hd * 128 + b) * 512 + c * 128) * 96;
#pragma unroll
  for (int nt = 0; nt < 6; ++nt) {
    const float4 bv = *(const float4*)&b2h[nt * 16 + q * 4];
#pragma unroll
    for (int sp = 0; sp < 2; ++sp) {
      const int s = (w * 2 + sp) * 16 + r;
      uint2 pk;
      pk.x = (uint32_t)f32_to_bf16(acc3[sp][nt][0] + bv.x) |
             ((uint32_t)f32_to_bf16(acc3[sp][nt][1] + bv.y) << 16);
      pk.y = (uint32_t)f32_to_bf16(acc3[sp][nt][2] + bv.z) |
             ((uint32_t)f32_to_bf16(acc3[sp][nt][3] + bv.w) << 16);
      *(uint2*)&aout[(size_t)s * 96 + nt * 16 + q * 4] = pk;
    }
  }
}

// ---------------- kernel 3: masked softmax over S + weighted pool ----------------
// (unchanged from R1)

__global__ __launch_bounds__(384) void softpool(
    const unsigned short* __restrict__ Hi,
    const unsigned short* __restrict__ Alog,
    const float* __restrict__ mask,  // B x S
    float* __restrict__ out) {       // B x 768
  __shared__ float bias[512];
  __shared__ float redl[32][96];
  __shared__ float redv[32][96];
  __shared__ float mfin[96];

  const int x = blockIdx.x;  // i*128 + b
  const int hd = x >> 7;
  const int b = x & 127;
  const int tid = threadIdx.x;
  const int g = tid / 12;
  const int t12 = tid - g * 12;
  const int h8 = t12 * 8;

  for (int s = tid; s < 512; s += 384)
    bias[s] = mask[b * 512 + s] > 0.5f ? 0.f : -1e30f;
  __syncthreads();

  const unsigned short* abase = Alog + (size_t)x * 512 * 96;
  const unsigned short* hbase = Hi + (size_t)x * 512 * 96;

  float m[8];
#pragma unroll
  for (int j = 0; j < 8; ++j) m[j] = -3e30f;
#pragma unroll
  for (int it = 0; it < 16; ++it) {
    const int s = g * 16 + it;
    bf16x8 a = *(const bf16x8*)&abase[(size_t)s * 96 + h8];
    const float bs = bias[s];
#pragma unroll
    for (int j = 0; j < 8; ++j)
      m[j] = fmaxf(m[j], bf16_to_f32((unsigned short)a[j]) + bs);
  }
#pragma unroll
  for (int j = 0; j < 8; ++j) redl[g][h8 + j] = m[j];
  __syncthreads();
  if (tid < 96) {
    float mm = -3e30f;
#pragma unroll
    for (int gg = 0; gg < 32; ++gg) mm = fmaxf(mm, redl[gg][tid]);
    mfin[tid] = mm;
  }
  __syncthreads();
  float mf[8];
#pragma unroll
  for (int j = 0; j < 8; ++j) mf[j] = mfin[h8 + j];
  __syncthreads();

  float l[8], v[8];
#pragma unroll
  for (int j = 0; j < 8; ++j) { l[j] = 0.f; v[j] = 0.f; }
#pragma unroll
  for (int it = 0; it < 16; ++it) {
    const int s = g * 16 + it;
    bf16x8 a = *(const bf16x8*)&abase[(size_t)s * 96 + h8];
    bf16x8 hv = *(const bf16x8*)&hbase[(size_t)s * 96 + h8];
    const float bs = bias[s];
#pragma unroll
    for (int j = 0; j < 8; ++j) {
      float e = __expf(bf16_to_f32((unsigned short)a[j]) + bs - mf[j]);
      l[j] += e;
      v[j] += e * bf16_to_f32((unsigned short)hv[j]);
    }
  }
#pragma unroll
  for (int j = 0; j < 8; ++j) {
    redl[g][h8 + j] = l[j];
    redv[g][h8 + j] = v[j];
  }
  __syncthreads();
  if (tid < 96) {
    float ls = 0.f, vs = 0.f;
#pragma unroll
    for (int gg = 0; gg < 32; ++gg) { ls += redl[gg][tid]; vs += redv[gg][tid]; }
    out[b * 768 + hd * 96 + tid] = vs / ls;
  }
}

// ---------------- launcher ----------------

extern "C" void kernel_launch(void* const* d_in, const int* in_sizes, int n_in,
                              void* d_out, int out_size, void* d_ws, size_t ws_size,
                              hipStream_t stream) {
  const float* X    = (const float*)d_in[0];
  const float* mask = (const float*)d_in[1];
  const float* P    = (const float*)d_in[2];
  const float* bP   = (const float*)d_in[3];
  const float* W1   = (const float*)d_in[4];
  const float* b1   = (const float*)d_in[5];
  const float* W2   = (const float*)d_in[6];
  const float* b2   = (const float*)d_in[7];
  float* out = (float*)d_out;
  (void)in_sizes; (void)n_in; (void)out_size; (void)ws_size;

  unsigned short* Xbf  = (unsigned short*)d_ws;
  unsigned short* Pbf  = Xbf + N_X;
  unsigned short* W1bf = Pbf + N_P;
  unsigned short* W2bf = W1bf + N_W1;
  unsigned short* Hi   = W2bf + N_W2;
  unsigned short* Alog = Hi + N_HI;

  cast_f32_bf16<<<N_X / 4 / 256, 256, 0, stream>>>(X, Xbf, N_X / 4);
  cast_f32_bf16<<<N_P / 4 / 256, 256, 0, stream>>>(P, Pbf, N_P / 4);
  cast_f32_bf16<<<N_W1 / 4 / 256, 256, 0, stream>>>(W1, W1bf, N_W1 / 4);
  cast_f32_bf16<<<N_W2 / 4 / 256, 256, 0, stream>>>(W2, W2bf, N_W2 / 4);

  gemm_hi<<<dim3(6, 512), 256, 0, stream>>>(Xbf, Pbf, bP, Hi);
  mlp_logits<<<8 * 128 * 4, 256, 0, stream>>>(Hi, W1bf, W2bf, b1, b2, Alog);
  softpool<<<8 * 128, 384, 0, stream>>>(Hi, Alog, mask, out);
}